// Round 11
// baseline (154.935 us; speedup 1.0000x reference)
//
#include <hip/hip_runtime.h>
#include <hip/hip_bf16.h>

#define TPB 256
#define Bsz 4
#define Nsp 1024
#define Cch 512
#define SEQ 77
#define CTX 768
#define EPSV 1e-5f
#define MTOK 4096   // B * N
#define SCL_L2E 0.18033688011111834f   // 0.125 * log2(e)

typedef __attribute__((ext_vector_type(8))) short s8v;
typedef __attribute__((ext_vector_type(4))) float f32x4;
typedef const __attribute__((address_space(1))) void* gas_t;
typedef __attribute__((address_space(3))) void* las_t;

static __device__ __forceinline__ float bf2f(short s) {
  union { unsigned u; float f; } z; z.u = ((unsigned)(unsigned short)s) << 16; return z.f;
}
static __device__ __forceinline__ short f2bf(float f) {
  union { __hip_bfloat16 h; short s; } u;
  u.h = __float2bfloat16(f);
  return u.s;
}
static __device__ __forceinline__ float fast_exp2(float x) {
  return __builtin_amdgcn_exp2f(x);
}
// tanh-form GELU via one v_exp_f32; clamped exponent. |err| ~3e-4 << bf16 ulp.
static __device__ __forceinline__ float fast_gelu(float v) {
  float s = v * (2.3021144f + 0.1029451f * v * v);
  s = fminf(fmaxf(s, -60.f), 60.f);
  float z = __builtin_amdgcn_exp2f(s);
  return v * z / (z + 1.f);
}

// ---------- prep: weight/ctx convert + SA gn partial stats + stats zero ----------
__global__ __launch_bounds__(TPB) void prep(const float* a0, const float* a1,
                                            const float* a2, const float* a3,
                                            const float* a4, const float* a5,
                                            const float* a6, short* __restrict__ wdst,
                                            const float* __restrict__ ctx,
                                            short* __restrict__ cdst,
                                            const float* __restrict__ x,
                                            float2* __restrict__ statsPart,
                                            float2* __restrict__ statsCA,
                                            float2* __restrict__ statsFFN) {
  int blk = blockIdx.x;
  int tid = threadIdx.x;
  if (blk < 4352) {
    int u = blk * TPB + tid;
    const float* src; int base;
    if      (u < 196608) { src = a0; base = 0; }
    else if (u < 262144) { src = a1; base = 196608; }
    else if (u < 327680) { src = a2; base = 262144; }
    else if (u < 524288) { src = a3; base = 327680; }
    else if (u < 589824) { src = a4; base = 524288; }
    else if (u < 851968) { src = a5; base = 589824; }
    else                 { src = a6; base = 851968; }
    float4 v = *(const float4*)(src + (size_t)(u - base) * 4);
    short4 o = make_short4(f2bf(v.x), f2bf(v.y), f2bf(v.z), f2bf(v.w));
    *(short4*)(wdst + (size_t)u * 4) = o;
    return;
  }
  if (blk < 4640) {
    int u = (blk - 4352) * TPB + tid;
    int row = u / 192, c4 = u - row * 192;
    int b = row / 96, s_ = row - b * 96;
    short4 o;
    if (s_ < SEQ) {
      float4 v = *(const float4*)(ctx + ((size_t)(b * SEQ + s_)) * CTX + c4 * 4);
      o = make_short4(f2bf(v.x), f2bf(v.y), f2bf(v.z), f2bf(v.w));
    } else {
      o = make_short4(0, 0, 0, 0);
    }
    *(short4*)(cdst + (size_t)row * CTX + c4 * 4) = o;
    return;
  }
  int idx = blk - 4640;
  int bg = idx >> 3, part = idx & 7;
  const float* base = x + (size_t)bg * 65536 + part * 8192;
  float s = 0.f, s2 = 0.f;
#pragma unroll
  for (int it = 0; it < 8; ++it) {
    float4 v = ((const float4*)base)[it * 256 + tid];
    s += v.x + v.y + v.z + v.w;
    s2 += v.x * v.x + v.y * v.y + v.z * v.z + v.w * v.w;
  }
  for (int off = 1; off < 64; off <<= 1) {
    s += __shfl_xor(s, off, 64);
    s2 += __shfl_xor(s2, off, 64);
  }
  __shared__ float red[2][4];
  int wid = tid >> 6;
  if ((tid & 63) == 0) { red[0][wid] = s; red[1][wid] = s2; }
  __syncthreads();
  if (tid == 0) {
    float S = red[0][0] + red[0][1] + red[0][2] + red[0][3];
    float S2 = red[1][0] + red[1][1] + red[1][2] + red[1][3];
    statsPart[idx] = make_float2(S, S2);
  } else if (tid == 1 && part == 0) {
    statsCA[bg] = make_float2(0.f, 0.f);
  } else if (tid == 2 && part == 0) {
    statsFFN[bg] = make_float2(0.f, 0.f);
  }
}

// ---------- GroupNorm apply + transpose: cm (f32 or bf16) -> token-major bf16 ----------
template<int INBF>
__global__ __launch_bounds__(TPB) void gn_apply(const void* __restrict__ xin,
                                                const float* __restrict__ w,
                                                const float* __restrict__ bb,
                                                const float2* __restrict__ stats,
                                                short* __restrict__ outp,
                                                int npart) {
  int t = blockIdx.x, bg = blockIdx.y;
  int b = bg >> 3, g = bg & 7;
  float S = 0.f, S2 = 0.f;
  for (int p = 0; p < npart; ++p) {
    float2 st = stats[bg * npart + p];
    S += st.x; S2 += st.y;
  }
  const float inv = 1.f / 65536.f;
  float mu = S * inv;
  float var = S2 * inv - mu * mu;
  float rstd = rsqrtf(var + EPSV);
  __shared__ float tile[64][65];
  int tid = threadIdx.x;
  int n0 = t * 64;
#pragma unroll
  for (int it = 0; it < 4; ++it) {
    int idx = it * 256 + tid;
    int c = idx >> 4, n4 = (idx & 15) * 4;
    float vx, vy, vz, vw;
    if (INBF) {
      const short* p = (const short*)xin + (size_t)bg * 65536;
      short4 v = *(const short4*)(p + (size_t)c * 1024 + n0 + n4);
      vx = bf2f(v.x); vy = bf2f(v.y); vz = bf2f(v.z); vw = bf2f(v.w);
    } else {
      const float* p = (const float*)xin + (size_t)bg * 65536;
      float4 v = *(const float4*)(p + (size_t)c * 1024 + n0 + n4);
      vx = v.x; vy = v.y; vz = v.z; vw = v.w;
    }
    float wc = w[g * 64 + c] * rstd;
    float bc = bb[g * 64 + c] - mu * wc;
    tile[c][n4 + 0] = vx * wc + bc;
    tile[c][n4 + 1] = vy * wc + bc;
    tile[c][n4 + 2] = vz * wc + bc;
    tile[c][n4 + 3] = vw * wc + bc;
  }
  __syncthreads();
  int n = tid >> 2, cs = (tid & 3) * 16;
  short ob[16];
#pragma unroll
  for (int j = 0; j < 16; ++j) ob[j] = f2bf(tile[cs + j][n]);
  short* op = outp + (size_t)(b * 1024 + n0 + n) * 512 + g * 64 + cs;
  *(int4*)op = *(int4*)&ob[0];
  *(int4*)(op + 8) = *(int4*)&ob[8];
}

// ---------- bf16 MFMA NT-GEMM, 2-phase double-buffered staging ----------
// MODE 0 : bf16 tm out, scaled by oscale
// MODE 2 : gelu -> bf16 tm out
// MODE 10: cm bf16 out + f32 cm resid + stats
// MODE 11: cm bf16 out + bf16 cm resid + stats
// MODE 12: cm f32 out (d_out) + bf16 cm resid, no stats
template<int BM, int BN, int MODE>
__global__ __launch_bounds__(TPB) void gemm_nt(const short* __restrict__ A,
                                               const short* __restrict__ Bw,
                                               const float* __restrict__ bias,
                                               const void* __restrict__ resid,
                                               void* __restrict__ outp,
                                               int K, int O,
                                               float oscale,
                                               float2* __restrict__ stats_out) {
  const int FM = BM / 32, FN = BN / 32;
  __shared__ __align__(16) short As[2][BM * 64];
  __shared__ __align__(16) short Bs[2][BN * 64];
  int tid = threadIdx.x;
  int lane = tid & 63, w = tid >> 6;
  int wr = w >> 1, wc = w & 1;
  int m0 = blockIdx.x * BM, o0 = blockIdx.y * BN;
  f32x4 acc[FM][FN];
#pragma unroll
  for (int i = 0; i < FM; ++i)
#pragma unroll
    for (int j = 0; j < FN; ++j) acc[i][j] = (f32x4){0.f, 0.f, 0.f, 0.f};
  int nk = K >> 6;

  auto stage = [&](int bi, int kt) {
    int k0 = kt << 6;
#pragma unroll
    for (int i = 0; i < BM / 32; ++i) {
      int c = i * 256 + tid;
      int r = c >> 3, qs = c & 7, qg = qs ^ (r & 7);
      const char* ga = (const char*)(A + ((size_t)(m0 + r) * K + k0)) + (qg << 4);
      __builtin_amdgcn_global_load_lds((gas_t)ga, (las_t)((char*)As[bi] + (c << 4)), 16, 0, 0);
    }
#pragma unroll
    for (int i = 0; i < BN / 32; ++i) {
      int c = i * 256 + tid;
      int r = c >> 3, qs = c & 7, qg = qs ^ (r & 7);
      const char* gb = (const char*)(Bw + ((size_t)(o0 + r) * K + k0)) + (qg << 4);
      __builtin_amdgcn_global_load_lds((gas_t)gb, (las_t)((char*)Bs[bi] + (c << 4)), 16, 0, 0);
    }
  };

  stage(0, 0);
  __syncthreads();
  for (int kt = 0; kt < nk; ++kt) {
    int cur = kt & 1;
    if (kt + 1 < nk) stage(cur ^ 1, kt + 1);
#pragma unroll
    for (int kk = 0; kk < 2; ++kk) {
      s8v a[FM], bfr[FN];
#pragma unroll
      for (int m = 0; m < FM; ++m) {
        int r = wr * (BM / 2) + m * 16 + (lane & 15);
        int q = (lane >> 4) + (kk << 2);
        a[m] = *(const s8v*)((const char*)As[cur] + r * 128 + ((q ^ (r & 7)) << 4));
      }
#pragma unroll
      for (int n = 0; n < FN; ++n) {
        int r = wc * (BN / 2) + n * 16 + (lane & 15);
        int q = (lane >> 4) + (kk << 2);
        bfr[n] = *(const s8v*)((const char*)Bs[cur] + r * 128 + ((q ^ (r & 7)) << 4));
      }
#pragma unroll
      for (int m = 0; m < FM; ++m)
#pragma unroll
        for (int n = 0; n < FN; ++n)
          acc[m][n] = __builtin_amdgcn_mfma_f32_16x16x32_bf16(a[m], bfr[n], acc[m][n], 0, 0, 0);
    }
    __syncthreads();
  }
  float bv[FN];
#pragma unroll
  for (int n = 0; n < FN; ++n) bv[n] = bias[o0 + wc * (BN / 2) + n * 16 + (lane & 15)];
  int row_b = m0 + wr * (BM / 2) + ((lane >> 4) << 2);
  int col_b = o0 + wc * (BN / 2) + (lane & 15);
  if (MODE >= 10) {
    float ls = 0.f, ls2 = 0.f;
#pragma unroll
    for (int m = 0; m < FM; ++m) {
      int t0 = row_b + m * 16;
      int b = t0 >> 10, n_ = t0 & 1023;
#pragma unroll
      for (int n = 0; n < FN; ++n) {
        int og = col_b + n * 16;
        size_t idx = ((size_t)(b * O + og)) * 1024 + n_;
        float rv[4];
        if (MODE == 10) {
          float4 r4 = *(const float4*)((const float*)resid + idx);
          rv[0] = r4.x; rv[1] = r4.y; rv[2] = r4.z; rv[3] = r4.w;
        } else {
          short4 r4 = *(const short4*)((const short*)resid + idx);
          rv[0] = bf2f(r4.x); rv[1] = bf2f(r4.y); rv[2] = bf2f(r4.z); rv[3] = bf2f(r4.w);
        }
        float ov[4];
#pragma unroll
        for (int j = 0; j < 4; ++j) ov[j] = acc[m][n][j] + bv[n] + rv[j];
        if (MODE == 12) {
          *(float4*)((float*)outp + idx) = make_float4(ov[0], ov[1], ov[2], ov[3]);
        } else {
          *(short4*)((short*)outp + idx) =
              make_short4(f2bf(ov[0]), f2bf(ov[1]), f2bf(ov[2]), f2bf(ov[3]));
          ls += ov[0] + ov[1] + ov[2] + ov[3];
          ls2 += ov[0] * ov[0] + ov[1] * ov[1] + ov[2] * ov[2] + ov[3] * ov[3];
        }
      }
    }
    if (MODE != 12 && stats_out != nullptr) {
      float s = ls, s2 = ls2;
      for (int off = 1; off < 64; off <<= 1) {
        s += __shfl_xor(s, off, 64);
        s2 += __shfl_xor(s2, off, 64);
      }
      __syncthreads();
      float* red = (float*)As;
      if (lane == 0) { red[w * 2] = s; red[w * 2 + 1] = s2; }
      __syncthreads();
      if (tid == 0) {
        float S = red[0] + red[2] + red[4] + red[6];
        float S2 = red[1] + red[3] + red[5] + red[7];
        int bg = (m0 >> 10) * 8 + (o0 >> 6);
        atomicAdd((float*)stats_out + bg * 2, S);
        atomicAdd((float*)stats_out + bg * 2 + 1, S2);
      }
    }
    return;
  }
#pragma unroll
  for (int m = 0; m < FM; ++m) {
#pragma unroll
    for (int i = 0; i < 4; ++i) {
      int mg = row_b + m * 16 + i;
#pragma unroll
      for (int n = 0; n < FN; ++n) {
        int og = col_b + n * 16;
        float v = acc[m][n][i] + bv[n];
        size_t idx = (size_t)mg * O + og;
        if (MODE == 2) {
          ((short*)outp)[idx] = f2bf(fast_gelu(v));
        } else {
          ((short*)outp)[idx] = f2bf(v * oscale);
        }
      }
    }
  }
}

// ---------- merged qkv + ca_kv GEMM, 2-phase dbuf: 408 blocks, 128x128 tiles ----------
__global__ __launch_bounds__(TPB) void gemm_qkvkv(
    const short* __restrict__ hb, const short* __restrict__ wqkv, const float* __restrict__ bqkv,
    const short* __restrict__ ctxb, const short* __restrict__ wkv, const float* __restrict__ bkv,
    short* __restrict__ qkvb, short* __restrict__ vt,
    short* __restrict__ kvb, short* __restrict__ cavt) {
  __shared__ __align__(16) short As[2][128 * 64];
  __shared__ __align__(16) short Bs[2][128 * 64];
  int bid = blockIdx.x;
  const short *A, *Bw; const float* bias;
  short *outp, *tout;
  int K, O, m0, o0, split, tstride, qsplit;
  if (bid < 384) {
    A = hb; Bw = wqkv; bias = bqkv; outp = qkvb; tout = vt;
    K = 512; O = 1536; split = 1024; tstride = 4096; qsplit = 512;
    m0 = (bid & 31) * 128; o0 = (bid >> 5) * 128;
  } else {
    int idx = bid - 384;
    A = ctxb; Bw = wkv; bias = bkv; outp = kvb; tout = cavt;
    K = 768; O = 1024; split = 512; tstride = 384; qsplit = 0;
    m0 = (idx % 3) * 128; o0 = (idx / 3) * 128;
  }
  int tid = threadIdx.x;
  int lane = tid & 63, w = tid >> 6;
  int wr = w >> 1, wc = w & 1;
  f32x4 acc[4][4];
#pragma unroll
  for (int i = 0; i < 4; ++i)
#pragma unroll
    for (int j = 0; j < 4; ++j) acc[i][j] = (f32x4){0.f, 0.f, 0.f, 0.f};
  int nk = K >> 6;

  auto stage = [&](int bi, int kt) {
    int k0 = kt << 6;
#pragma unroll
    for (int i = 0; i < 4; ++i) {
      int c = i * 256 + tid;
      int r = c >> 3, qs = c & 7, qg = qs ^ (r & 7);
      const char* ga = (const char*)(A + ((size_t)(m0 + r) * K + k0)) + (qg << 4);
      __builtin_amdgcn_global_load_lds((gas_t)ga, (las_t)((char*)As[bi] + (c << 4)), 16, 0, 0);
    }
#pragma unroll
    for (int i = 0; i < 4; ++i) {
      int c = i * 256 + tid;
      int r = c >> 3, qs = c & 7, qg = qs ^ (r & 7);
      const char* gb = (const char*)(Bw + ((size_t)(o0 + r) * K + k0)) + (qg << 4);
      __builtin_amdgcn_global_load_lds((gas_t)gb, (las_t)((char*)Bs[bi] + (c << 4)), 16, 0, 0);
    }
  };

  stage(0, 0);
  __syncthreads();
  for (int kt = 0; kt < nk; ++kt) {
    int cur = kt & 1;
    if (kt + 1 < nk) stage(cur ^ 1, kt + 1);
#pragma unroll
    for (int kk = 0; kk < 2; ++kk) {
      s8v a[4], bfr[4];
#pragma unroll
      for (int m = 0; m < 4; ++m) {
        int r = wr * 64 + m * 16 + (lane & 15);
        int q = (lane >> 4) + (kk << 2);
        a[m] = *(const s8v*)((const char*)As[cur] + r * 128 + ((q ^ (r & 7)) << 4));
      }
#pragma unroll
      for (int n = 0; n < 4; ++n) {
        int r = wc * 64 + n * 16 + (lane & 15);
        int q = (lane >> 4) + (kk << 2);
        bfr[n] = *(const s8v*)((const char*)Bs[cur] + r * 128 + ((q ^ (r & 7)) << 4));
      }
#pragma unroll
      for (int m = 0; m < 4; ++m)
#pragma unroll
        for (int n = 0; n < 4; ++n)
          acc[m][n] = __builtin_amdgcn_mfma_f32_16x16x32_bf16(a[m], bfr[n], acc[m][n], 0, 0, 0);
    }
    __syncthreads();
  }
  float bv[4];
#pragma unroll
  for (int n = 0; n < 4; ++n) bv[n] = bias[o0 + wc * 64 + n * 16 + (lane & 15)];
  int row_b = m0 + wr * 64 + ((lane >> 4) << 2);
  int col_b = o0 + wc * 64 + (lane & 15);
  if (o0 >= split) {
#pragma unroll
    for (int m = 0; m < 4; ++m) {
#pragma unroll
      for (int n = 0; n < 4; ++n) {
        int og = col_b + n * 16;
        short4 s4 = make_short4(f2bf(acc[m][n][0] + bv[n]), f2bf(acc[m][n][1] + bv[n]),
                                f2bf(acc[m][n][2] + bv[n]), f2bf(acc[m][n][3] + bv[n]));
        *(short4*)(tout + (size_t)(og - split) * tstride + row_b + m * 16) = s4;
      }
    }
    return;
  }
#pragma unroll
  for (int m = 0; m < 4; ++m) {
#pragma unroll
    for (int i = 0; i < 4; ++i) {
      int mg = row_b + m * 16 + i;
#pragma unroll
      for (int n = 0; n < 4; ++n) {
        int og = col_b + n * 16;
        float v = acc[m][n][i] + bv[n];
        if (og < qsplit) v *= SCL_L2E;
        ((short*)outp)[(size_t)mg * O + og] = f2bf(v);
      }
    }
  }
}

// ---------- self-attention, MFMA flash: 8-wave blocks (128 q-rows), KVBLK=128, dbuf ----------
// Halves K/V tile re-staging vs 4-wave blocks: 256 blocks x (K,V full pass) instead of 512.
__global__ __launch_bounds__(512) void sa_attn_mfma(const short* __restrict__ qkv,
                                                    const short* __restrict__ vt,
                                                    short* __restrict__ outp) {
  __shared__ __align__(16) short Ks[2][128 * 64];
  __shared__ __align__(16) short Vs[2][64 * 128];
  __shared__ __align__(16) short Ps[8][16 * 128];
  int b = blockIdx.z, h = blockIdx.y, q0 = blockIdx.x * 128;
  int tid = threadIdx.x, lane = tid & 63, w = tid >> 6;
  int g = lane >> 4, qi = lane & 15;
  s8v qf[2];
  {
    const short* qp = qkv + (size_t)(b * 1024 + q0 + w * 16 + qi) * 1536 + h * 64 + g * 8;
    qf[0] = *(const s8v*)qp;
    qf[1] = *(const s8v*)(qp + 32);
  }
  f32x4 o[4];
#pragma unroll
  for (int d = 0; d < 4; ++d) o[d] = (f32x4){0.f, 0.f, 0.f, 0.f};
  float mrun = -1e30f, lrun = 0.f;
  const short* kbase = qkv + (size_t)(b * 1024) * 1536 + 512 + h * 64;
  const short* vbase = vt + (size_t)(h * 64) * 4096 + b * 1024;
  char* psw = (char*)Ps + w * 4096;
  int pswz = (qi & 15) << 4;

  auto stage = [&](int bufi, int kt) {
    int k0 = kt * 128;
#pragma unroll
    for (int i = 0; i < 2; ++i) {            // K: 128 rows x 8 slots = 1024 chunks
      int c = i * 512 + tid;
      int r = c >> 3, cs = c & 7, cg = cs ^ (r & 7);
      const char* gp = (const char*)(kbase + (size_t)(k0 + r) * 1536) + (cg << 4);
      __builtin_amdgcn_global_load_lds((gas_t)gp, (las_t)((char*)Ks[bufi] + (c << 4)), 16, 0, 0);
    }
#pragma unroll
    for (int i = 0; i < 2; ++i) {            // V^T: 64 rows x 16 slots = 1024 chunks
      int c = i * 512 + tid;
      int r = c >> 4, cs = c & 15, cg = cs ^ (r & 15);
      const char* gp = (const char*)(vbase + (size_t)r * 4096 + k0) + (cg << 4);
      __builtin_amdgcn_global_load_lds((gas_t)gp, (las_t)((char*)Vs[bufi] + (c << 4)), 16, 0, 0);
    }
  };

  stage(0, 0);
  __syncthreads();
  for (int kt = 0; kt < 8; ++kt) {
    int cur = kt & 1;
    if (kt < 7) stage(cur ^ 1, kt + 1);
    f32x4 st[8];
#pragma unroll
    for (int t = 0; t < 8; ++t) st[t] = (f32x4){0.f, 0.f, 0.f, 0.f};
    __builtin_amdgcn_s_setprio(1);
#pragma unroll
    for (int s = 0; s < 2; ++s) {
#pragma unroll
      for (int t = 0; t < 8; ++t) {
        int r = t * 16 + qi;
        s8v kf = *(const s8v*)((const char*)Ks[cur] + r * 128 + (((s * 4 + g) ^ (r & 7)) << 4));
        st[t] = __builtin_amdgcn_mfma_f32_16x16x32_bf16(kf, qf[s], st[t], 0, 0, 0);
      }
    }
    __builtin_amdgcn_s_setprio(0);
    float sv[32];
#pragma unroll
    for (int t = 0; t < 8; ++t)
#pragma unroll
      for (int r2 = 0; r2 < 4; ++r2) sv[t * 4 + r2] = st[t][r2];
    float mx = sv[0];
#pragma unroll
    for (int i = 1; i < 32; ++i) mx = fmaxf(mx, sv[i]);
    mx = fmaxf(mx, __shfl_xor(mx, 16));
    mx = fmaxf(mx, __shfl_xor(mx, 32));
    if (!__all(mx - mrun <= 11.f)) {
      float mnew = fmaxf(mrun, mx);
      float scale = fast_exp2(mrun - mnew);
      lrun *= scale;
#pragma unroll
      for (int d = 0; d < 4; ++d) o[d] *= scale;
      mrun = mnew;
    }
    float psum = 0.f;
#pragma unroll
    for (int i = 0; i < 32; ++i) { sv[i] = fast_exp2(sv[i] - mrun); psum += sv[i]; }
    psum += __shfl_xor(psum, 16);
    psum += __shfl_xor(psum, 32);
    lrun += psum;
#pragma unroll
    for (int t = 0; t < 8; ++t) {
      short4 pk = make_short4(f2bf(sv[t * 4]), f2bf(sv[t * 4 + 1]),
                              f2bf(sv[t * 4 + 2]), f2bf(sv[t * 4 + 3]));
      *(short4*)(psw + qi * 256 + ((t * 32 + g * 8) ^ pswz)) = pk;
    }
    __builtin_amdgcn_s_setprio(1);
#pragma unroll
    for (int s = 0; s < 4; ++s) {
      s8v bf = *(const s8v*)(psw + qi * 256 + ((s * 64 + g * 16) ^ pswz));
#pragma unroll
      for (int d = 0; d < 4; ++d) {
        int r = d * 16 + qi;
        s8v af = *(const s8v*)((const char*)Vs[cur] + r * 256 + (((s * 4 + g) ^ (r & 15)) << 4));
        o[d] = __builtin_amdgcn_mfma_f32_16x16x32_bf16(af, bf, o[d], 0, 0, 0);
      }
    }
    __builtin_amdgcn_s_setprio(0);
    __syncthreads();
  }
  float rl = 1.f / lrun;
  short* ob = outp + (size_t)(b * 1024 + q0 + w * 16 + qi) * 512 + h * 64;
#pragma unroll
  for (int d = 0; d < 4; ++d) {
    short4 s4 = make_short4(f2bf(o[d][0] * rl), f2bf(o[d][1] * rl),
                            f2bf(o[d][2] * rl), f2bf(o[d][3] * rl));
    *(short4*)(ob + d * 16 + g * 4) = s4;
  }
}

// ---------- cross-attention, MFMA single-pass (q pre-scaled, exp2) ----------
__global__ __launch_bounds__(TPB) void ca_attn_mfma(const short* __restrict__ qb,
                                                    const short* __restrict__ kvb,
                                                    const short* __restrict__ cavt,
                                                    short* __restrict__ outp) {
  __shared__ __align__(16) short Ks[96 * 64];
  __shared__ __align__(16) short Vs[64 * 128];
  __shared__ __align__(16) short Ps[4][16 * 128];
  int b = blockIdx.z, h = blockIdx.y, q0 = blockIdx.x * 64;
  int tid = threadIdx.x, lane = tid & 63, w = tid >> 6;
  int g = lane >> 4, qi = lane & 15;
  s8v qf[2];
  {
    const short* qp = qb + (size_t)(b * 1024 + q0 + w * 16 + qi) * 512 + h * 64 + g * 8;
    qf[0] = *(const s8v*)qp;
    qf[1] = *(const s8v*)(qp + 32);
  }
  const short* kbase = kvb + (size_t)(b * 96) * 1024 + h * 64;
#pragma unroll
  for (int i = 0; i < 3; ++i) {
    int c = i * 256 + tid;
    int r = c >> 3, cs = c & 7, cg = cs ^ (r & 7);
    const char* gp = (const char*)(kbase + (size_t)r * 1024) + (cg << 4);
    __builtin_amdgcn_global_load_lds((gas_t)gp, (las_t)((char*)Ks + (c << 4)), 16, 0, 0);
  }
#pragma unroll
  for (int i = 0; i < 3; ++i) {
    int c = i * 256 + tid;
    int r = c / 12, jj = c - r * 12;
    int4 dv = *(const int4*)(cavt + (size_t)(h * 64 + r) * 384 + b * 96 + jj * 8);
    *(int4*)((char*)Vs + r * 256 + ((jj * 16) ^ ((r & 7) << 4))) = dv;
  }
  __syncthreads();
  f32x4 st[6];
#pragma unroll
  for (int t = 0; t < 6; ++t) st[t] = (f32x4){0.f, 0.f, 0.f, 0.f};
  __builtin_amdgcn_s_setprio(1);
#pragma unroll
  for (int s = 0; s < 2; ++s) {
#pragma unroll
    for (int t = 0; t < 6; ++t) {
      int r = t * 16 + qi;
      s8v kf = *(const s8v*)((const char*)Ks + r * 128 + (((s * 4 + g) ^ (r & 7)) << 4));
      st[t] = __builtin_amdgcn_mfma_f32_16x16x32_bf16(kf, qf[s], st[t], 0, 0, 0);
    }
  }
  __builtin_amdgcn_s_setprio(0);
  float sv[24];
#pragma unroll
  for (int t = 0; t < 6; ++t)
#pragma unroll
    for (int r2 = 0; r2 < 4; ++r2) {
      int key = t * 16 + g * 4 + r2;
      sv[t * 4 + r2] = (key < SEQ) ? st[t][r2] : -1e30f;
    }
  float mx = sv[0];
#pragma unroll
  for (int i = 1; i < 24; ++i) mx = fmaxf(mx, sv[i]);
  mx = fmaxf(mx, __shfl_xor(mx, 16));
  mx = fmaxf(mx, __shfl_xor(mx, 32));
  float l = 0.f;
#pragma unroll
  for (int i = 0; i < 24; ++i) { sv[i] = fast_exp2(sv[i] - mx); l += sv[i]; }
  l += __shfl_xor(l, 16);
  l += __shfl_xor(l, 32);
  char* psw = (char*)Ps + w * 4096;
  int pswz = (qi & 7) << 4;
#pragma unroll
  for (int t = 0; t < 6; ++t) {
    short4 pk = make_short4(f2bf(sv[t * 4]), f2bf(sv[t * 4 + 1]),
                            f2bf(sv[t * 4 + 2]), f2bf(sv[t * 4 + 3]));
    *(short4*)(psw + qi * 256 + ((t * 32 + g * 8) ^ pswz)) = pk;
  }
  f32x4 o[4];
#pragma unroll
  for (int d = 0; d < 4; ++d) o[d] = (f32x4){0.f, 0.f, 0.f, 0.f};
  __builtin_amdgcn_s_setprio(1);
#pragma unroll
  for (int s = 0; s < 3; ++s) {
    s8v bf = *(const s8v*)(psw + qi * 256 + ((s * 64 + g * 16) ^ pswz));
#pragma unroll
    for (int d = 0; d < 4; ++d) {
      int r = d * 16 + qi;
      s8v af = *(const s8v*)((const char*)Vs + r * 256 + (((s * 64 + g * 16) ^ ((r & 7) << 4))));
      o[d] = __builtin_amdgcn_mfma_f32_16x16x32_bf16(af, bf, o[d], 0, 0, 0);
    }
  }
  __builtin_amdgcn_s_setprio(0);
  float rl = 1.f / l;
  short* ob = outp + (size_t)(b * 1024 + q0 + w * 16 + qi) * 512 + h * 64;
#pragma unroll
  for (int d = 0; d < 4; ++d) {
    short4 s4 = make_short4(f2bf(o[d][0] * rl), f2bf(o[d][1] * rl),
                            f2bf(o[d][2] * rl), f2bf(o[d][3] * rl));
    *(short4*)(ob + d * 16 + g * 4) = s4;
  }
}

extern "C" void kernel_launch(void* const* d_in, const int* in_sizes, int n_in,
                              void* d_out, int out_size, void* d_ws, size_t ws_size,
                              hipStream_t stream) {
  const float* x        = (const float*)d_in[0];
  const float* context  = (const float*)d_in[1];
  const float* sa_nw    = (const float*)d_in[2];
  const float* sa_nb    = (const float*)d_in[3];
  const float* sa_qkv_w = (const float*)d_in[4];
  const float* sa_qkv_b = (const float*)d_in[5];
  const float* sa_pw    = (const float*)d_in[6];
  const float* sa_pb    = (const float*)d_in[7];
  const float* ca_nw    = (const float*)d_in[8];
  const float* ca_nb    = (const float*)d_in[9];
  const float* ca_qw    = (const float*)d_in[10];
  const float* ca_qb    = (const float*)d_in[11];
  const float* ca_kvw   = (const float*)d_in[12];
  const float* ca_kvb   = (const float*)d_in[13];
  const float* ca_pw    = (const float*)d_in[14];
  const float* ca_pb    = (const float*)d_in[15];
  const float* ff_nw    = (const float*)d_in[16];
  const float* ff_nb    = (const float*)d_in[17];
  const float* ff_w1    = (const float*)d_in[18];
  const float* ff_b1    = (const float*)d_in[19];
  const float* ff_w2    = (const float*)d_in[20];
  const float* ff_b2    = (const float*)d_in[21];
  float* outp = (float*)d_out;

  char* ws = (char*)d_ws;
  short*  xcur  = (short*)(ws);                          // [0,4M)  residual stream (cm bf16)
  short*  hb    = (short*)(ws + (4u << 20));             // [4,8M)  GN out / attn out (bf16 tm)
  short*  big   = (short*)(ws + (8u << 20));             // [8,24M) qkvb / qb / h1
  short*  qkvb  = big;
  short*  qb    = big;
  short*  h1    = big;
  short*  vt    = (short*)(ws + (24u << 20));            // [24,28M) V^T [512][4096]
  short*  kvb   = (short*)(ws + (28u << 20));            // 768KB
  short*  cavt  = (short*)(ws + (29u << 20));            // 384KB [512][384]
  short*  ctxb  = (short*)(ws + (30u << 20));            // 576KB
  float2* statsPart = (float2*)(ws + (31u << 20));       // [32][8] partials (SA)
  float2* statsCA   = statsPart + 256;                   // 32 raw sums (CA)
  float2* statsFFN  = statsPart + 288;                   // 32 raw sums (FFN)
  short*  wb    = (short*)(ws + (32u << 20));            // bf16 weights (~8.7MB)

  short* w_qkv = wb;
  short* w_sap = wb + 786432;
  short* w_caq = wb + 1048576;
  short* w_kv  = wb + 1310720;
  short* w_cap = wb + 2097152;
  short* w_f1  = wb + 2359296;
  short* w_f2  = wb + 3407872;

  dim3 blk(TPB);
  prep<<<4896, blk, 0, stream>>>(sa_qkv_w, sa_pw, ca_qw, ca_kvw, ca_pw, ff_w1, ff_w2, wb,
                                 context, ctxb, x, statsPart, statsCA, statsFFN);

  // ---- self-attention (+ merged CA kv projection) ----
  gn_apply<0><<<dim3(16, 32), blk, 0, stream>>>(x, sa_nw, sa_nb, statsPart, hb, 8);
  gemm_qkvkv<<<408, blk, 0, stream>>>(hb, w_qkv, sa_qkv_b, ctxb, w_kv, ca_kvb,
                                      qkvb, vt, kvb, cavt);
  sa_attn_mfma<<<dim3(8, 8, 4), dim3(512), 0, stream>>>(qkvb, vt, hb);
  gemm_nt<128, 64, 10><<<dim3(32, 8), blk, 0, stream>>>(hb, w_sap, sa_pb, x, xcur, 512, 512, 1.f, statsCA);

  // ---- cross-attention ----
  gn_apply<1><<<dim3(16, 32), blk, 0, stream>>>(xcur, ca_nw, ca_nb, statsCA, hb, 1);
  gemm_nt<128, 64, 0><<<dim3(32, 8), blk, 0, stream>>>(hb, w_caq, ca_qb, nullptr, qb, 512, 512, SCL_L2E, nullptr);
  ca_attn_mfma<<<dim3(16, 8, 4), blk, 0, stream>>>(qb, kvb, cavt, hb);
  gemm_nt<128, 64, 11><<<dim3(32, 8), blk, 0, stream>>>(hb, w_cap, ca_pb, xcur, xcur, 512, 512, 1.f, statsFFN);

  // ---- FFN ----
  gn_apply<1><<<dim3(16, 32), blk, 0, stream>>>(xcur, ff_nw, ff_nb, statsFFN, hb, 1);
  gemm_nt<128, 128, 2><<<dim3(32, 16), blk, 0, stream>>>(hb, w_f1, ff_b1, nullptr, h1, 512, 2048, 1.f, nullptr);
  gemm_nt<128, 64, 12><<<dim3(32, 8), blk, 0, stream>>>(h1, w_f2, ff_b2, xcur, outp, 2048, 512, 1.f, nullptr);
}